// Round 13
// baseline (223.253 us; speedup 1.0000x reference)
//
#include <hip/hip_runtime.h>

// ReluGalois: y = Horner(coeff, x), degree 8 (9 coefficients), float32 in/out.
// 33,554,432 elements = 8,388,608 float4s (exact, no tail).
// Ladder: R5 regular ld/st grid-stride = 83us (3.05 TB/s program bytes).
// R7 nt-load+nt-store = ~68us. R10 one-shot full grid (TLP probe) = ~66us,
// structure exonerated. R11 single-variable probe: REGULAR load (input is
// half L3-resident from the harness restore copy -- let it hit Infinity
// Cache) + NT store (keep stores from thrashing L3). One float4 per thread,
// full grid, no loop.

#define NCOEF 9

typedef float f32x4 __attribute__((ext_vector_type(4)));

__global__ __launch_bounds__(256) void relu_galois_poly(
    const f32x4* __restrict__ xv,
    const float* __restrict__ coeff,
    f32x4* __restrict__ ov)
{
    // Coefficients: uniform-address loads -> scalar loads, broadcast.
    float c[NCOEF];
#pragma unroll
    for (int i = 0; i < NCOEF; ++i) c[i] = coeff[i];

    const int i = blockIdx.x * 256 + threadIdx.x;  // grid sized exactly to n4

    // Regular (allocating) load: exploit L3-resident input lines.
    f32x4 v = xv[i];

    f32x4 a = {c[0], c[0], c[0], c[0]};
#pragma unroll
    for (int k = 1; k < NCOEF; ++k) {
        f32x4 ck = {c[k], c[k], c[k], c[k]};
        a = a * v + ck;  // contracts to v_fma
    }

    // nt store: single-use stream, don't evict input lines from L3.
    __builtin_nontemporal_store(a, ov + i);
}

// Fallback for sizes not divisible by (4*256) -- not hit for 8x2048x2048.
__global__ __launch_bounds__(256) void relu_galois_poly_tail(
    const float* __restrict__ x,
    const float* __restrict__ coeff,
    float* __restrict__ out,
    int n, int start)
{
    float c[NCOEF];
#pragma unroll
    for (int i = 0; i < NCOEF; ++i) c[i] = coeff[i];
    int i = start + blockIdx.x * 256 + threadIdx.x;
    if (i < n) {
        float v = x[i];
        float a = c[0];
#pragma unroll
        for (int k = 1; k < NCOEF; ++k) a = fmaf(a, v, c[k]);
        out[i] = a;
    }
}

extern "C" void kernel_launch(void* const* d_in, const int* in_sizes, int n_in,
                              void* d_out, int out_size, void* d_ws, size_t ws_size,
                              hipStream_t stream) {
    const float* x     = (const float*)d_in[0];
    const float* coeff = (const float*)d_in[1];
    float* out         = (float*)d_out;

    const int n  = in_sizes[0];      // 33,554,432
    const int n4 = n / 4;            // 8,388,608 float4s

    const int block = 256;
    const int grid  = n4 / block;    // 32,768 blocks, exact for our shape

    relu_galois_poly<<<grid, block, 0, stream>>>(
        (const f32x4*)x, coeff, (f32x4*)out);

    const int done = grid * block * 4;  // == n for our shape
    if (done < n) {
        const int rem = n - done;
        relu_galois_poly_tail<<<(rem + block - 1) / block, block, 0, stream>>>(
            x, coeff, out, n, done);
    }
}

// Round 14
// 219.827 us; speedup vs baseline: 1.0156x; 1.0156x over previous
//
#include <hip/hip_runtime.h>

// ReluGalois: y = Horner(coeff, x), degree 8 (9 coefficients), float32 in/out.
// 33,554,432 elements = 8,388,608 float4s (exact, no tail).
// FINAL config (measured-best, R10): nt load + nt store, one float4/thread,
// full grid, no loop. Ladder of measured probes:
//   R5  regular ld/st, grid-stride:        kernel 83us, bench 235.8
//   R7  nt ld + nt st, grid-stride:        bench 221.2  (+12% -- the lever)
//   R10 nt ld + nt st, one-shot full grid: bench 218.8  (best)
//   R13 regular ld + nt st, one-shot:      bench 223.3  (read path: nt wins)
// Exonerated by counters: compute (VALUBusy 5%), over-fetch (FETCH+WRITE =
// exact bytes), LDS conflicts (0), occupancy (fills do 6.7 TB/s @ 9.6% occ),
// MLP depth (R5), dispatch structure (R10), read alloc policy (R13).
// Residual gap to 6.3 TB/s clean-copy ceiling attributed to harness-state
// L3 dirty-drain contention from the 640 MB of poison fills preceding the
// kernel in the replayed graph -- not addressable from kernel code.

#define NCOEF 9

typedef float f32x4 __attribute__((ext_vector_type(4)));

__global__ __launch_bounds__(256) void relu_galois_poly(
    const f32x4* __restrict__ xv,
    const float* __restrict__ coeff,
    f32x4* __restrict__ ov)
{
    // Coefficients: uniform-address loads -> scalar loads, broadcast.
    float c[NCOEF];
#pragma unroll
    for (int i = 0; i < NCOEF; ++i) c[i] = coeff[i];

    const int i = blockIdx.x * 256 + threadIdx.x;  // grid sized exactly to n4

    // nt load: single-use stream, bypass L3 allocation (measured >= regular).
    f32x4 v = __builtin_nontemporal_load(xv + i);

    f32x4 a = {c[0], c[0], c[0], c[0]};
#pragma unroll
    for (int k = 1; k < NCOEF; ++k) {
        f32x4 ck = {c[k], c[k], c[k], c[k]};
        a = a * v + ck;  // contracts to v_fma
    }

    // nt store: don't write-allocate / thrash L3 (the +12% lever, R7).
    __builtin_nontemporal_store(a, ov + i);
}

// Fallback for sizes not divisible by (4*256) -- not hit for 8x2048x2048.
__global__ __launch_bounds__(256) void relu_galois_poly_tail(
    const float* __restrict__ x,
    const float* __restrict__ coeff,
    float* __restrict__ out,
    int n, int start)
{
    float c[NCOEF];
#pragma unroll
    for (int i = 0; i < NCOEF; ++i) c[i] = coeff[i];
    int i = start + blockIdx.x * 256 + threadIdx.x;
    if (i < n) {
        float v = x[i];
        float a = c[0];
#pragma unroll
        for (int k = 1; k < NCOEF; ++k) a = fmaf(a, v, c[k]);
        out[i] = a;
    }
}

extern "C" void kernel_launch(void* const* d_in, const int* in_sizes, int n_in,
                              void* d_out, int out_size, void* d_ws, size_t ws_size,
                              hipStream_t stream) {
    const float* x     = (const float*)d_in[0];
    const float* coeff = (const float*)d_in[1];
    float* out         = (float*)d_out;

    const int n  = in_sizes[0];      // 33,554,432
    const int n4 = n / 4;            // 8,388,608 float4s

    const int block = 256;
    const int grid  = n4 / block;    // 32,768 blocks, exact for our shape

    relu_galois_poly<<<grid, block, 0, stream>>>(
        (const f32x4*)x, coeff, (f32x4*)out);

    const int done = grid * block * 4;  // == n for our shape
    if (done < n) {
        const int rem = n - done;
        relu_galois_poly_tail<<<(rem + block - 1) / block, block, 0, stream>>>(
            x, coeff, out, n, done);
    }
}